// Round 6
// baseline (378.194 us; speedup 1.0000x reference)
//
#include <hip/hip_runtime.h>

typedef unsigned short ushort_t;
typedef unsigned int uint_t;
typedef __attribute__((ext_vector_type(8))) short bhalf8;   // 8 bf16 (4 VGPRs)
typedef __attribute__((ext_vector_type(4))) float f32x4;

#define C_LIN  0.04419417382415922f     // 1/sqrt(512)
#define C_CONV 0.014731391274719738f    // 1/sqrt(512*9)

__device__ __forceinline__ ushort_t f2bf(float f) {
    uint_t u = __float_as_uint(f);
    u += 0x7fffu + ((u >> 16) & 1u);    // round-to-nearest-even
    return (ushort_t)(u >> 16);
}

__device__ __forceinline__ void gload16(const void* g, void* l) {
    __builtin_amdgcn_global_load_lds((const __attribute__((address_space(1))) void*)g,
                                     (__attribute__((address_space(3))) void*)l, 16, 0, 0);
}

// ---------------- mapping-network layer: zout = act(zin @ (w*C_LIN)^T + b) --
__global__ void map_layer_k(const float* __restrict__ zin, const float* __restrict__ w,
                            const float* __restrict__ bias, const float* __restrict__ alpha,
                            float* __restrict__ zout, int final_) {
    __shared__ float zs[512];
    const int b = blockIdx.y, tid = threadIdx.x;
    if (tid < 128) ((float4*)zs)[tid] = ((const float4*)(zin + b * 512))[tid];
    __syncthreads();
    const int j = blockIdx.x * 64 + (tid >> 2);
    const int part = (tid & 3) * 128;
    const float4* wr = (const float4*)(w + (size_t)j * 512 + part);
    const float* zp = zs + part;
    float acc = 0.f;
#pragma unroll 8
    for (int i = 0; i < 32; ++i) {
        float4 w4 = wr[i];
        acc += w4.x * zp[4*i] + w4.y * zp[4*i+1] + w4.z * zp[4*i+2] + w4.w * zp[4*i+3];
    }
    acc += __shfl_xor(acc, 1);
    acc += __shfl_xor(acc, 2);
    if ((tid & 3) == 0) {
        acc = acc * C_LIN + bias[j];
        if (final_) acc *= C_CONV;                       // fold c_conv into style
        else        acc = acc >= 0.f ? acc : alpha[j] * acc;
        zout[b * 512 + j] = acc;
    }
}

// ---- fused prep: wsq[co][ci] = sum_tap cw^2 ; wbf[tap][co][ci] = bf16(cw) --
__global__ void wsqbf_k(const float* __restrict__ cw, float* __restrict__ wsq,
                        ushort_t* __restrict__ wbf) {
    int idx = blockIdx.x * 256 + threadIdx.x;   // cout*512 + ci, < 262144
    const float* p = cw + (size_t)idx * 9;
    float v[9], sum = 0.f;
#pragma unroll
    for (int k = 0; k < 9; ++k) { v[k] = p[k]; sum += v[k] * v[k]; }
    wsq[idx] = sum;
#pragma unroll
    for (int k = 0; k < 9; ++k)
        wbf[(size_t)k * 262144 + idx] = f2bf(v[k]);
}

// ---------------- sigma_inv[b][cout], 256 blocks ----------------------------
__global__ void sigma_k(const float* __restrict__ style_c, const float* __restrict__ wsq,
                        float* __restrict__ sig) {
    __shared__ float s2[512];
    const int b = blockIdx.y, cb = blockIdx.x, tid = threadIdx.x;
    if (tid < 128) {
        float4 sv = ((const float4*)(style_c + b * 512))[tid];
        s2[4*tid]   = sv.x * sv.x; s2[4*tid+1] = sv.y * sv.y;
        s2[4*tid+2] = sv.z * sv.z; s2[4*tid+3] = sv.w * sv.w;
    }
    __syncthreads();
    const int c = cb * 32 + (tid >> 3);
    const int part = (tid & 7) * 64;
    const float4* wr = (const float4*)(wsq + (size_t)c * 512 + part);
    const float* zp = s2 + part;
    float acc = 0.f;
#pragma unroll
    for (int i = 0; i < 16; ++i) {
        float4 w = wr[i];
        acc += w.x * zp[4*i] + w.y * zp[4*i+1] + w.z * zp[4*i+2] + w.w * zp[4*i+3];
    }
    acc += __shfl_xor(acc, 1);
    acc += __shfl_xor(acc, 2);
    acc += __shfl_xor(acc, 4);
    if ((tid & 7) == 0) sig[b * 512 + c] = 1.0f / sqrtf(acc + 1e-8f);
}

// ---------------- x -> bf16 NHWC, style-modulated ---------------------------
__global__ void xmod_k(const float* __restrict__ x, const float* __restrict__ style_c,
                       ushort_t* __restrict__ xm) {
    const int y = blockIdx.x, b = blockIdx.y, tid = threadIdx.x;
    const float* xp = x + ((size_t)b * 512) * 4096 + y * 64;            // x[b][ci][y][0]
    ushort_t* op = xm + (((size_t)b * 64 + y) * 64) * 512;              // xm[b][y][x][ci]
    __shared__ ushort_t tile[32][68];
    for (int cin0 = 0; cin0 < 512; cin0 += 32) {
#pragma unroll
        for (int t = 0; t < 2; ++t) {                                   // float4 loads
            int i = tid + t * 256;                                      // < 512
            int ci = i >> 4, x4 = i & 15;
            float4 v = *(const float4*)(xp + (size_t)(cin0 + ci) * 4096 + x4 * 4);
            float sc = style_c[b * 512 + cin0 + ci];
            tile[ci][x4*4]   = f2bf(v.x * sc); tile[ci][x4*4+1] = f2bf(v.y * sc);
            tile[ci][x4*4+2] = f2bf(v.z * sc); tile[ci][x4*4+3] = f2bf(v.w * sc);
        }
        __syncthreads();
#pragma unroll
        for (int t = 0; t < 4; ++t) {                                   // ushort2 stores
            int i = tid + t * 256;                                      // < 1024
            int xc = i >> 4, c2 = i & 15;
            ushort2 pr;
            pr.x = tile[c2*2][xc]; pr.y = tile[c2*2+1][xc];
            *(ushort2*)(op + (size_t)xc * 512 + cin0 + c2 * 2) = pr;
        }
        __syncthreads();
    }
}

// ---------------- implicit-GEMM conv via 16x16x32 MFMA ----------------------
// Round-3 structure + double-buffered 2-phase pipeline (T3 minimum):
//   prologue: stage chunk0 -> drain -> barrier
//   iter t:   issue stage(t+1) into buf^1, compute buf, drain+barrier
// Block: 64 couts x (8 rows x 64 cols); 4 waves, each 64 couts x 2 rows.
// 1 block/CU (159744 B LDS) -- prefetch replaces cross-block overlap.
// LDS sigma-swizzle on 16B blocks within 32-block windows:
//   physical (k=bits[4:3], s=bits[2:0]) holds logical (pos = s^2k, group k).
template <bool XPRE>
__global__ __launch_bounds__(256, 1)
void conv_k(const float* __restrict__ x, const ushort_t* __restrict__ xm,
            const ushort_t* __restrict__ wbf, const float* __restrict__ style_c,
            const float* __restrict__ sig, float* __restrict__ out) {
    __shared__ __align__(16) ushort_t wt[2][18432];   // 2 x 36864 B
    __shared__ __align__(16) ushort_t xs[2][21504];   // 2 x 43008 B (2688 16B-blocks)

    const int tid  = threadIdx.x;
    const int lane = tid & 63;
    const int wv   = tid >> 6;
    const int l15  = lane & 15, l4 = lane >> 4;

    // XCD-aware bijective block swizzle (nwg=1024, 8 XCDs): batch-major chunks.
    const int bid = blockIdx.x;
    const int swz = (bid & 7) * 128 + (bid >> 3);
    const int b     = swz >> 6;
    const int cout0 = ((swz >> 3) & 7) * 64;
    const int r0    = (swz & 7) * 8;

    const int nx = (wv < 2) ? 11 : 10;             // X slots per wave (42 total)

    // ---- per-thread staging source offsets (element units, +c0 per chunk)
    int gw[9];
#pragma unroll
    for (int t = 0; t < 9; ++t) {
        int L = (wv * 9 + t) * 64 + lane;          // physical 16B-block in wt
        int tap = L >> 8, win = (L >> 5) & 7, k = (L >> 3) & 3, s = L & 7;
        int c = win * 8 + ((s ^ (k * 2)) & 7);     // logical cout_local
        gw[t] = ((tap * 512 + cout0 + c) << 9) + k * 8;
    }
    int gxo[11];
#pragma unroll
    for (int t = 0; t < 11; ++t) {
        if (t < nx) {
            int L = (wv + 4 * t) * 64 + lane;      // physical block in xs, slot u=wv+4t
            int k = (L >> 3) & 3, s = L & 7;
            int p = ((L >> 5) << 3) | ((s ^ (k * 2)) & 7);
            p = min(p, 659);                        // pad-region lanes: safe duplicate
            int row = p / 66, col = p - row * 66;
            int gy = min(max(r0 - 1 + row, 0), 63);
            int gx = min(max(col - 1, 0), 63);
            gxo[t] = (((b * 64 + gy) * 64 + gx) << 9) + k * 8;   // xm element offset
        } else gxo[t] = 0;
    }

    f32x4 acc[2][4][4] = {};
    const int base_af = (l15 >> 3) * 512 + l4 * 128 + (((l15 & 7) ^ (l4 * 2)) & 7) * 16;

    auto stage = [&](int c0, int pb) {
#pragma unroll
        for (int t = 0; t < 9; ++t)
            gload16(wbf + gw[t] + c0, (char*)wt[pb] + (wv * 9 + t) * 1024);
        if (XPRE) {
#pragma unroll
            for (int t = 0; t < 11; ++t)
                if (t < nx)
                    gload16(xm + gxo[t] + c0, (char*)xs[pb] + (wv + 4 * t) * 1024);
        } else {
#pragma unroll
            for (int t = 0; t < 11; ++t) {
                if (t < nx) {
                    int L = (wv + 4 * t) * 64 + lane;
                    int k = (L >> 3) & 3, s = L & 7;
                    int p = ((L >> 5) << 3) | ((s ^ (k * 2)) & 7);
                    p = min(p, 659);
                    int row = p / 66, col = p - row * 66;
                    int gy = min(max(r0 - 1 + row, 0), 63);
                    int gx = min(max(col - 1, 0), 63);
                    const float* xp = x + ((size_t)(b * 512 + c0 + k * 8)) * 4096 + gy * 64 + gx;
                    const float* sc = style_c + b * 512 + c0 + k * 8;
                    ushort_t tmp[8];
#pragma unroll
                    for (int e = 0; e < 8; ++e)
                        tmp[e] = f2bf(xp[(size_t)e * 4096] * sc[e]);
                    *(bhalf8*)((char*)xs[pb] + (size_t)L * 16) = *(const bhalf8*)tmp;
                }
            }
        }
    };

    // ---- prologue: stage chunk 0
    stage(0, 0);
    asm volatile("s_waitcnt vmcnt(0)" ::: "memory");
    __syncthreads();

    for (int it = 0; it < 16; ++it) {
        const int cur = it & 1;
        if (it < 15) stage((it + 1) * 32, cur ^ 1);   // prefetch next chunk

        const char* wtc = (const char*)wt[cur];
        const char* xsc = (const char*)xs[cur];

        // ---- compute: dx-major, af held for all dy, bfr per input row
#pragma unroll
        for (int dx = 0; dx < 3; ++dx) {
            bhalf8 af[3][4];
#pragma unroll
            for (int dy = 0; dy < 3; ++dy)
#pragma unroll
                for (int m = 0; m < 4; ++m)
                    af[dy][m] = *(const bhalf8*)(wtc + base_af + (dy * 3 + dx) * 4096 + m * 1024);
#pragma unroll
            for (int ri = 0; ri < 4; ++ri) {
                const int p0 = (wv * 2 + ri) * 66 + dx + l15;
                const int bb = (p0 >> 3) * 512 + l4 * 128 + (((p0 & 7) ^ (l4 * 2)) & 7) * 16;
                bhalf8 bfr[4];
#pragma unroll
                for (int n = 0; n < 4; ++n)
                    bfr[n] = *(const bhalf8*)(xsc + bb + n * 1024);
#pragma unroll
                for (int dy = 0; dy < 3; ++dy) {
                    const int r_out = ri - dy;
                    if (r_out < 0 || r_out > 1) continue;
#pragma unroll
                    for (int m = 0; m < 4; ++m)
#pragma unroll
                        for (int n = 0; n < 4; ++n)
                            acc[r_out][m][n] = __builtin_amdgcn_mfma_f32_16x16x32_bf16(
                                af[dy][m], bfr[n], acc[r_out][m][n], 0, 0, 0);
                }
            }
        }
        // drain AFTER compute: prefetch had the whole chunk to land -> cheap
        asm volatile("s_waitcnt vmcnt(0)" ::: "memory");
        __syncthreads();
    }

    // ---- epilogue: demodulate + store (C/D: col=lane&15, row=(lane>>4)*4+reg)
#pragma unroll
    for (int r_out = 0; r_out < 2; ++r_out) {
        const int orow = r0 + wv * 2 + r_out;
#pragma unroll
        for (int m = 0; m < 4; ++m) {
#pragma unroll
            for (int r = 0; r < 4; ++r) {
                int cout = cout0 + m * 16 + l4 * 4 + r;
                float sg = sig[b * 512 + cout];
                float* op = out + (((size_t)b * 512 + cout) * 64 + orow) * 64;
#pragma unroll
                for (int n = 0; n < 4; ++n)
                    op[n * 16 + l15] = acc[r_out][m][n][r] * sg;
            }
        }
    }
}

// ---------------- launch ----------------------------------------------------
extern "C" void kernel_launch(void* const* d_in, const int* in_sizes, int n_in,
                              void* d_out, int out_size, void* d_ws, size_t ws_size,
                              hipStream_t stream) {
    const float* x  = (const float*)d_in[0];
    const float* s  = (const float*)d_in[1];
    const float* w0 = (const float*)d_in[2];
    const float* b0 = (const float*)d_in[3];
    const float* a0 = (const float*)d_in[4];
    const float* w1 = (const float*)d_in[5];
    const float* b1 = (const float*)d_in[6];
    const float* a1 = (const float*)d_in[7];
    const float* sw = (const float*)d_in[8];
    const float* sb = (const float*)d_in[9];
    const float* cw = (const float*)d_in[10];
    float* out = (float*)d_out;

    // workspace layout (f32 elements unless noted)
    float*    style_c = (float*)d_ws;                       // 8192
    float*    sig     = style_c + 8192;                     // 8192
    float*    zt0     = sig + 8192;                         // 8192
    float*    zt1     = zt0 + 8192;                         // 8192
    float*    wsq     = zt1 + 8192;                         // 262144
    ushort_t* wbf     = (ushort_t*)(wsq + 262144);          // 2359296 bf16
    ushort_t* xm      = (ushort_t*)((char*)d_ws + 5898240); // 33554432 bf16 (67.1 MB)
    const bool xpre = ws_size >= 73007104ull;

    wsqbf_k<<<1024, 256, 0, stream>>>(cw, wsq, wbf);
    map_layer_k<<<dim3(8, 16), 256, 0, stream>>>(s,   w0, b0, a0, zt0,     0);
    map_layer_k<<<dim3(8, 16), 256, 0, stream>>>(zt0, w1, b1, a1, zt1,     0);
    map_layer_k<<<dim3(8, 16), 256, 0, stream>>>(zt1, sw, sb, a1, style_c, 1);
    sigma_k<<<dim3(16, 16), 256, 0, stream>>>(style_c, wsq, sig);
    if (xpre) {
        xmod_k<<<dim3(64, 16), 256, 0, stream>>>(x, style_c, xm);
        conv_k<true><<<1024, 256, 0, stream>>>(x, xm, wbf, style_c, sig, out);
    } else {
        conv_k<false><<<1024, 256, 0, stream>>>(x, xm, wbf, style_c, sig, out);
    }
}

// Round 7
// 332.586 us; speedup vs baseline: 1.1371x; 1.1371x over previous
//
#include <hip/hip_runtime.h>

typedef unsigned short ushort_t;
typedef unsigned int uint_t;
typedef __attribute__((ext_vector_type(8))) short bhalf8;   // 8 bf16 (4 VGPRs)
typedef __attribute__((ext_vector_type(4))) float f32x4;

#define C_LIN  0.04419417382415922f     // 1/sqrt(512)
#define C_CONV 0.014731391274719738f    // 1/sqrt(512*9)

__device__ __forceinline__ ushort_t f2bf(float f) {
    uint_t u = __float_as_uint(f);
    u += 0x7fffu + ((u >> 16) & 1u);    // round-to-nearest-even
    return (ushort_t)(u >> 16);
}

__device__ __forceinline__ void gload16(const void* g, void* l) {
    __builtin_amdgcn_global_load_lds((const __attribute__((address_space(1))) void*)g,
                                     (__attribute__((address_space(3))) void*)l, 16, 0, 0);
}

// ---------------- mapping-network layer: zout = act(zin @ (w*C_LIN)^T + b) --
__global__ void map_layer_k(const float* __restrict__ zin, const float* __restrict__ w,
                            const float* __restrict__ bias, const float* __restrict__ alpha,
                            float* __restrict__ zout, int final_) {
    __shared__ float zs[512];
    const int b = blockIdx.y, tid = threadIdx.x;
    if (tid < 128) ((float4*)zs)[tid] = ((const float4*)(zin + b * 512))[tid];
    __syncthreads();
    const int j = blockIdx.x * 64 + (tid >> 2);
    const int part = (tid & 3) * 128;
    const float4* wr = (const float4*)(w + (size_t)j * 512 + part);
    const float* zp = zs + part;
    float acc = 0.f;
#pragma unroll 8
    for (int i = 0; i < 32; ++i) {
        float4 w4 = wr[i];
        acc += w4.x * zp[4*i] + w4.y * zp[4*i+1] + w4.z * zp[4*i+2] + w4.w * zp[4*i+3];
    }
    acc += __shfl_xor(acc, 1);
    acc += __shfl_xor(acc, 2);
    if ((tid & 3) == 0) {
        acc = acc * C_LIN + bias[j];
        if (final_) acc *= C_CONV;                       // fold c_conv into style
        else        acc = acc >= 0.f ? acc : alpha[j] * acc;
        zout[b * 512 + j] = acc;
    }
}

// ---- fused prep: wsq[co][ci] = sum_tap cw^2 ; wbf[tap][co][ci] = bf16(cw) --
__global__ void wsqbf_k(const float* __restrict__ cw, float* __restrict__ wsq,
                        ushort_t* __restrict__ wbf) {
    int idx = blockIdx.x * 256 + threadIdx.x;   // cout*512 + ci, < 262144
    const float* p = cw + (size_t)idx * 9;
    float v[9], sum = 0.f;
#pragma unroll
    for (int k = 0; k < 9; ++k) { v[k] = p[k]; sum += v[k] * v[k]; }
    wsq[idx] = sum;
#pragma unroll
    for (int k = 0; k < 9; ++k)
        wbf[(size_t)k * 262144 + idx] = f2bf(v[k]);
}

// ---------------- sigma_inv[b][cout], 256 blocks ----------------------------
__global__ void sigma_k(const float* __restrict__ style_c, const float* __restrict__ wsq,
                        float* __restrict__ sig) {
    __shared__ float s2[512];
    const int b = blockIdx.y, cb = blockIdx.x, tid = threadIdx.x;
    if (tid < 128) {
        float4 sv = ((const float4*)(style_c + b * 512))[tid];
        s2[4*tid]   = sv.x * sv.x; s2[4*tid+1] = sv.y * sv.y;
        s2[4*tid+2] = sv.z * sv.z; s2[4*tid+3] = sv.w * sv.w;
    }
    __syncthreads();
    const int c = cb * 32 + (tid >> 3);
    const int part = (tid & 7) * 64;
    const float4* wr = (const float4*)(wsq + (size_t)c * 512 + part);
    const float* zp = s2 + part;
    float acc = 0.f;
#pragma unroll
    for (int i = 0; i < 16; ++i) {
        float4 w = wr[i];
        acc += w.x * zp[4*i] + w.y * zp[4*i+1] + w.z * zp[4*i+2] + w.w * zp[4*i+3];
    }
    acc += __shfl_xor(acc, 1);
    acc += __shfl_xor(acc, 2);
    acc += __shfl_xor(acc, 4);
    if ((tid & 7) == 0) sig[b * 512 + c] = 1.0f / sqrtf(acc + 1e-8f);
}

// ---------------- x -> bf16 NHWC, style-modulated ---------------------------
__global__ void xmod_k(const float* __restrict__ x, const float* __restrict__ style_c,
                       ushort_t* __restrict__ xm) {
    const int y = blockIdx.x, b = blockIdx.y, tid = threadIdx.x;
    const float* xp = x + ((size_t)b * 512) * 4096 + y * 64;            // x[b][ci][y][0]
    ushort_t* op = xm + (((size_t)b * 64 + y) * 64) * 512;              // xm[b][y][x][ci]
    __shared__ ushort_t tile[32][68];
    for (int cin0 = 0; cin0 < 512; cin0 += 32) {
#pragma unroll
        for (int t = 0; t < 2; ++t) {                                   // float4 loads
            int i = tid + t * 256;                                      // < 512
            int ci = i >> 4, x4 = i & 15;
            float4 v = *(const float4*)(xp + (size_t)(cin0 + ci) * 4096 + x4 * 4);
            float sc = style_c[b * 512 + cin0 + ci];
            tile[ci][x4*4]   = f2bf(v.x * sc); tile[ci][x4*4+1] = f2bf(v.y * sc);
            tile[ci][x4*4+2] = f2bf(v.z * sc); tile[ci][x4*4+3] = f2bf(v.w * sc);
        }
        __syncthreads();
#pragma unroll
        for (int t = 0; t < 4; ++t) {                                   // ushort2 stores
            int i = tid + t * 256;                                      // < 1024
            int xc = i >> 4, c2 = i & 15;
            ushort2 pr;
            pr.x = tile[c2*2][xc]; pr.y = tile[c2*2+1][xc];
            *(ushort2*)(op + (size_t)xc * 512 + cin0 + c2 * 2) = pr;
        }
        __syncthreads();
    }
}

// ---------------- implicit-GEMM conv via 16x16x32 MFMA ----------------------
// 512-thread block: 128 couts x 8 rows x 64 cols; 8 waves = 2 co-halves x
// 4 row-quarters; each wave = 64 co x 2 rows (round-3-proven wave tile).
// 1 block/CU (= 2 waves/SIMD). X double-buffered (prefetch during compute);
// W single-buffered (staged after compute barrier; wbf is L2-hot -> short
// drain). LDS 73728 + 2*43008 = 159744 B.
// 16B-block sigma-swizzle in 32-block windows: physical (k=bits[4:3],
// s=bits[2:0]) holds logical (pos = s^2k, group k).
template <bool XPRE>
__global__ __launch_bounds__(512, 2)
void conv_k(const float* __restrict__ x, const ushort_t* __restrict__ xm,
            const ushort_t* __restrict__ wbf, const float* __restrict__ style_c,
            const float* __restrict__ sig, float* __restrict__ out) {
    __shared__ __align__(16) ushort_t wt[36864];      // 73728 B: 9 tap x 128 co x 32 ci
    __shared__ __align__(16) ushort_t xs[2][21504];   // 2 x 43008 B (2688 16B-blocks)

    const int tid  = threadIdx.x;
    const int lane = tid & 63;
    const int wv   = tid >> 6;                 // 0..7
    const int ch   = wv >> 2;                  // co-half 0/1
    const int rq   = wv & 3;                   // row-quarter 0..3
    const int l15  = lane & 15, l4 = lane >> 4;

    // XCD-aware bijective swizzle (nwg=512, 8 XCDs): batch-major chunks.
    const int bid = blockIdx.x;
    const int swz = (bid & 7) * 64 + (bid >> 3);
    const int b     = swz >> 5;
    const int cout0 = ((swz >> 3) & 3) * 128;
    const int r0    = (swz & 7) * 8;

    const int nx = (wv < 2) ? 6 : 5;           // X slots per wave (42 total)

    // ---- X staging source offsets (element units, +c0 per chunk); slot u=wv+8t
    int gxo[6];
#pragma unroll
    for (int t = 0; t < 6; ++t) {
        if (t < nx) {
            int L = (wv + 8 * t) * 64 + lane;
            int k = (L >> 3) & 3, s = L & 7;
            int p = ((L >> 5) << 3) | ((s ^ (k * 2)) & 7);
            p = min(p, 659);                    // pad-region lanes: safe duplicate
            int row = p / 66, col = p - row * 66;
            int gy = min(max(r0 - 1 + row, 0), 63);
            int gx = min(max(col - 1, 0), 63);
            gxo[t] = (((b * 64 + gy) * 64 + gx) << 9) + k * 8;   // xm element offset
        } else gxo[t] = 0;
    }
    // ---- W staging source offsets; slot u = wv + 8t, t<9 (72 slots total)
    int gws[9];
#pragma unroll
    for (int t = 0; t < 9; ++t) {
        int L = (wv + 8 * t) * 64 + lane;      // physical 16B-block in wt
        int tap = L >> 9, win = (L >> 5) & 15, k = (L >> 3) & 3, s = L & 7;
        int c = win * 8 + ((s ^ (k * 2)) & 7); // logical cout_local (0..127)
        gws[t] = tap * 262144 + (cout0 + c) * 512 + k * 8;
    }

    f32x4 acc[2][4][4] = {};
    // A-frag byte base: blk = tap*512 + (ch*8 + m*2 + (l15>>3))*32 + l4*8 + ((l15&7)^(2*l4))
    const int base_af = (((ch * 8 + (l15 >> 3)) * 32) + l4 * 8 + ((l15 & 7) ^ (2 * l4))) * 16;

    auto stageX = [&](int c0, int pb) {
        if (XPRE) {
#pragma unroll
            for (int t = 0; t < 6; ++t)
                if (t < nx)
                    gload16(xm + gxo[t] + c0, (char*)xs[pb] + (wv + 8 * t) * 1024);
        } else {
#pragma unroll
            for (int t = 0; t < 6; ++t) {
                if (t < nx) {
                    int L = (wv + 8 * t) * 64 + lane;
                    int k = (L >> 3) & 3, s = L & 7;
                    int p = ((L >> 5) << 3) | ((s ^ (k * 2)) & 7);
                    p = min(p, 659);
                    int row = p / 66, col = p - row * 66;
                    int gy = min(max(r0 - 1 + row, 0), 63);
                    int gx = min(max(col - 1, 0), 63);
                    const float* xp = x + ((size_t)(b * 512 + c0 + k * 8)) * 4096 + gy * 64 + gx;
                    const float* sc = style_c + b * 512 + c0 + k * 8;
                    ushort_t tmp[8];
#pragma unroll
                    for (int e = 0; e < 8; ++e)
                        tmp[e] = f2bf(xp[(size_t)e * 4096] * sc[e]);
                    *(bhalf8*)((char*)xs[pb] + (size_t)L * 16) = *(const bhalf8*)tmp;
                }
            }
        }
    };
    auto stageW = [&](int c0) {
#pragma unroll
        for (int t = 0; t < 9; ++t)
            gload16(wbf + gws[t] + c0, (char*)wt + (wv + 8 * t) * 1024);
    };

    // ---- prologue: stage chunk 0 (W + X)
    stageW(0);
    stageX(0, 0);
    asm volatile("s_waitcnt vmcnt(0)" ::: "memory");
    __syncthreads();

    for (int it = 0; it < 16; ++it) {
        const int cur = it & 1;
        if (it < 15) stageX((it + 1) * 32, cur ^ 1);   // X prefetch flies under compute

        const char* wtc = (const char*)wt;
        const char* xsc = (const char*)xs[cur];

        // ---- compute: dx-major, af held for all dy, bfr per input row
#pragma unroll
        for (int dx = 0; dx < 3; ++dx) {
            bhalf8 af[3][4];
#pragma unroll
            for (int dy = 0; dy < 3; ++dy)
#pragma unroll
                for (int m = 0; m < 4; ++m)
                    af[dy][m] = *(const bhalf8*)(wtc + base_af + (dy * 3 + dx) * 8192 + m * 1024);
#pragma unroll
            for (int ri = 0; ri < 4; ++ri) {
                const int p0 = (rq * 2 + ri) * 66 + dx + l15;
                const int bb = (p0 >> 3) * 512 + l4 * 128 + (((p0 & 7) ^ (l4 * 2)) & 7) * 16;
                bhalf8 bfr[4];
#pragma unroll
                for (int n = 0; n < 4; ++n)
                    bfr[n] = *(const bhalf8*)(xsc + bb + n * 1024);
#pragma unroll
                for (int dy = 0; dy < 3; ++dy) {
                    const int r_out = ri - dy;
                    if (r_out < 0 || r_out > 1) continue;
#pragma unroll
                    for (int m = 0; m < 4; ++m)
#pragma unroll
                        for (int n = 0; n < 4; ++n)
                            acc[r_out][m][n] = __builtin_amdgcn_mfma_f32_16x16x32_bf16(
                                af[dy][m], bfr[n], acc[r_out][m][n], 0, 0, 0);
                }
            }
        }
        __syncthreads();                       // X(t+1) landed; all wt reads done
        if (it < 15) {
            stageW((it + 1) * 32);             // W re-stage (L2-hot, short drain)
            asm volatile("s_waitcnt vmcnt(0)" ::: "memory");
        }
        __syncthreads();
    }

    // ---- epilogue: demodulate + store (C/D: col=lane&15, row=(lane>>4)*4+reg)
#pragma unroll
    for (int r_out = 0; r_out < 2; ++r_out) {
        const int orow = r0 + rq * 2 + r_out;
#pragma unroll
        for (int m = 0; m < 4; ++m) {
#pragma unroll
            for (int r = 0; r < 4; ++r) {
                int cout = cout0 + ch * 64 + m * 16 + l4 * 4 + r;
                float sg = sig[b * 512 + cout];
                float* op = out + (((size_t)b * 512 + cout) * 64 + orow) * 64;
#pragma unroll
                for (int n = 0; n < 4; ++n)
                    op[n * 16 + l15] = acc[r_out][m][n][r] * sg;
            }
        }
    }
}

// ---------------- launch ----------------------------------------------------
extern "C" void kernel_launch(void* const* d_in, const int* in_sizes, int n_in,
                              void* d_out, int out_size, void* d_ws, size_t ws_size,
                              hipStream_t stream) {
    const float* x  = (const float*)d_in[0];
    const float* s  = (const float*)d_in[1];
    const float* w0 = (const float*)d_in[2];
    const float* b0 = (const float*)d_in[3];
    const float* a0 = (const float*)d_in[4];
    const float* w1 = (const float*)d_in[5];
    const float* b1 = (const float*)d_in[6];
    const float* a1 = (const float*)d_in[7];
    const float* sw = (const float*)d_in[8];
    const float* sb = (const float*)d_in[9];
    const float* cw = (const float*)d_in[10];
    float* out = (float*)d_out;

    // workspace layout (f32 elements unless noted)
    float*    style_c = (float*)d_ws;                       // 8192
    float*    sig     = style_c + 8192;                     // 8192
    float*    zt0     = sig + 8192;                         // 8192
    float*    zt1     = zt0 + 8192;                         // 8192
    float*    wsq     = zt1 + 8192;                         // 262144
    ushort_t* wbf     = (ushort_t*)(wsq + 262144);          // 2359296 bf16
    ushort_t* xm      = (ushort_t*)((char*)d_ws + 5898240); // 33554432 bf16 (67.1 MB)
    const bool xpre = ws_size >= 73007104ull;

    wsqbf_k<<<1024, 256, 0, stream>>>(cw, wsq, wbf);
    map_layer_k<<<dim3(8, 16), 256, 0, stream>>>(s,   w0, b0, a0, zt0,     0);
    map_layer_k<<<dim3(8, 16), 256, 0, stream>>>(zt0, w1, b1, a1, zt1,     0);
    map_layer_k<<<dim3(8, 16), 256, 0, stream>>>(zt1, sw, sb, a1, style_c, 1);
    sigma_k<<<dim3(16, 16), 256, 0, stream>>>(style_c, wsq, sig);
    if (xpre) {
        xmod_k<<<dim3(64, 16), 256, 0, stream>>>(x, style_c, xm);
        conv_k<true><<<512, 512, 0, stream>>>(x, xm, wbf, style_c, sig, out);
    } else {
        conv_k<false><<<512, 512, 0, stream>>>(x, xm, wbf, style_c, sig, out);
    }
}

// Round 8
// 301.480 us; speedup vs baseline: 1.2545x; 1.1032x over previous
//
#include <hip/hip_runtime.h>

typedef unsigned short ushort_t;
typedef unsigned int uint_t;
typedef __attribute__((ext_vector_type(8))) short bhalf8;   // 8 bf16 (4 VGPRs)
typedef __attribute__((ext_vector_type(4))) float f32x4;

#define C_LIN  0.04419417382415922f     // 1/sqrt(512)
#define C_CONV 0.014731391274719738f    // 1/sqrt(512*9)

__device__ __forceinline__ ushort_t f2bf(float f) {
    uint_t u = __float_as_uint(f);
    u += 0x7fffu + ((u >> 16) & 1u);    // round-to-nearest-even
    return (ushort_t)(u >> 16);
}

__device__ __forceinline__ void gload16(const void* g, void* l) {
    __builtin_amdgcn_global_load_lds((const __attribute__((address_space(1))) void*)g,
                                     (__attribute__((address_space(3))) void*)l, 16, 0, 0);
}

// ---------------- mapping-network layer: zout = act(zin @ (w*C_LIN)^T + b) --
__global__ void map_layer_k(const float* __restrict__ zin, const float* __restrict__ w,
                            const float* __restrict__ bias, const float* __restrict__ alpha,
                            float* __restrict__ zout, int final_) {
    __shared__ float zs[512];
    const int b = blockIdx.y, tid = threadIdx.x;
    if (tid < 128) ((float4*)zs)[tid] = ((const float4*)(zin + b * 512))[tid];
    __syncthreads();
    const int j = blockIdx.x * 64 + (tid >> 2);
    const int part = (tid & 3) * 128;
    const float4* wr = (const float4*)(w + (size_t)j * 512 + part);
    const float* zp = zs + part;
    float acc = 0.f;
#pragma unroll 8
    for (int i = 0; i < 32; ++i) {
        float4 w4 = wr[i];
        acc += w4.x * zp[4*i] + w4.y * zp[4*i+1] + w4.z * zp[4*i+2] + w4.w * zp[4*i+3];
    }
    acc += __shfl_xor(acc, 1);
    acc += __shfl_xor(acc, 2);
    if ((tid & 3) == 0) {
        acc = acc * C_LIN + bias[j];
        if (final_) acc *= C_CONV;                       // fold c_conv into style
        else        acc = acc >= 0.f ? acc : alpha[j] * acc;
        zout[b * 512 + j] = acc;
    }
}

// ---- fused prep: wsq[co][ci] = sum_tap cw^2 ; wbf3 chunk-major bf16(cw) ----
// wbf3 elem addr for (tap, co, ci): ((ci>>5)*9 + tap)*16384 + co*32 + (ci&31)
// -> per-chunk slice (all taps, all co, 32 ci) = 294912 B contiguous, L2-hot.
__global__ void wsqbf_k(const float* __restrict__ cw, float* __restrict__ wsq,
                        ushort_t* __restrict__ wbf3) {
    int idx = blockIdx.x * 256 + threadIdx.x;   // cout*512 + ci, < 262144
    int cout = idx >> 9, ci = idx & 511;
    const float* p = cw + (size_t)idx * 9;
    float v[9], sum = 0.f;
#pragma unroll
    for (int k = 0; k < 9; ++k) { v[k] = p[k]; sum += v[k] * v[k]; }
    wsq[idx] = sum;
    const size_t base = (size_t)(ci >> 5) * 9 * 16384 + cout * 32 + (ci & 31);
#pragma unroll
    for (int k = 0; k < 9; ++k)
        wbf3[base + (size_t)k * 16384] = f2bf(v[k]);
}

// ---------------- sigma_inv[b][cout], 256 blocks ----------------------------
__global__ void sigma_k(const float* __restrict__ style_c, const float* __restrict__ wsq,
                        float* __restrict__ sig) {
    __shared__ float s2[512];
    const int b = blockIdx.y, cb = blockIdx.x, tid = threadIdx.x;
    if (tid < 128) {
        float4 sv = ((const float4*)(style_c + b * 512))[tid];
        s2[4*tid]   = sv.x * sv.x; s2[4*tid+1] = sv.y * sv.y;
        s2[4*tid+2] = sv.z * sv.z; s2[4*tid+3] = sv.w * sv.w;
    }
    __syncthreads();
    const int c = cb * 32 + (tid >> 3);
    const int part = (tid & 7) * 64;
    const float4* wr = (const float4*)(wsq + (size_t)c * 512 + part);
    const float* zp = s2 + part;
    float acc = 0.f;
#pragma unroll
    for (int i = 0; i < 16; ++i) {
        float4 w = wr[i];
        acc += w.x * zp[4*i] + w.y * zp[4*i+1] + w.z * zp[4*i+2] + w.w * zp[4*i+3];
    }
    acc += __shfl_xor(acc, 1);
    acc += __shfl_xor(acc, 2);
    acc += __shfl_xor(acc, 4);
    if ((tid & 7) == 0) sig[b * 512 + c] = 1.0f / sqrtf(acc + 1e-8f);
}

// ---------------- x -> bf16 NHWC, style-modulated ---------------------------
__global__ void xmod_k(const float* __restrict__ x, const float* __restrict__ style_c,
                       ushort_t* __restrict__ xm) {
    const int y = blockIdx.x, b = blockIdx.y, tid = threadIdx.x;
    const float* xp = x + ((size_t)b * 512) * 4096 + y * 64;            // x[b][ci][y][0]
    ushort_t* op = xm + (((size_t)b * 64 + y) * 64) * 512;              // xm[b][y][x][ci]
    __shared__ ushort_t tile[32][68];
    for (int cin0 = 0; cin0 < 512; cin0 += 32) {
#pragma unroll
        for (int t = 0; t < 2; ++t) {                                   // float4 loads
            int i = tid + t * 256;                                      // < 512
            int ci = i >> 4, x4 = i & 15;
            float4 v = *(const float4*)(xp + (size_t)(cin0 + ci) * 4096 + x4 * 4);
            float sc = style_c[b * 512 + cin0 + ci];
            tile[ci][x4*4]   = f2bf(v.x * sc); tile[ci][x4*4+1] = f2bf(v.y * sc);
            tile[ci][x4*4+2] = f2bf(v.z * sc); tile[ci][x4*4+3] = f2bf(v.w * sc);
        }
        __syncthreads();
#pragma unroll
        for (int t = 0; t < 4; ++t) {                                   // ushort2 stores
            int i = tid + t * 256;                                      // < 1024
            int xc = i >> 4, c2 = i & 15;
            ushort2 pr;
            pr.x = tile[c2*2][xc]; pr.y = tile[c2*2+1][xc];
            *(ushort2*)(op + (size_t)xc * 512 + cin0 + c2 * 2) = pr;
        }
        __syncthreads();
    }
}

// ---------------- implicit-GEMM conv via 16x16x32 MFMA ----------------------
// Round-3 structure (proven 67% MfmaUtil): 2 blocks/CU, 256 threads, W+X
// single-buffered, stage -> drain -> compute per 32-ci chunk.
// + chunk-major W source (L2-hot slice -> short drain)
// + anti-phase stagger: one of each presumed co-resident pair (bid, bid+256)
//   sleeps ~3.8k cyc so its drains overlap the partner's compute.
// LDS sigma-swizzle on 16B blocks within 32-block windows:
//   physical (k=bits[4:3], s=bits[2:0]) holds logical (pos = s^2k, group k).
template <bool XPRE>
__global__ __launch_bounds__(256, 2)
void conv_k(const float* __restrict__ x, const ushort_t* __restrict__ xm,
            const ushort_t* __restrict__ wbf3, const float* __restrict__ style_c,
            const float* __restrict__ sig, float* __restrict__ out) {
    __shared__ __align__(16) ushort_t wt[18432];   // 36864 B: 9 taps x 64 co x 32 ci
    __shared__ __align__(16) ushort_t xs[21504];   // 43008 B: 2688 16B-blocks

    const int tid  = threadIdx.x;
    const int lane = tid & 63;
    const int wv   = tid >> 6;
    const int l15  = lane & 15, l4 = lane >> 4;

    // XCD-aware bijective block swizzle (nwg=1024, 8 XCDs): batch-major chunks.
    const int bid = blockIdx.x;
    const int swz = (bid & 7) * 128 + (bid >> 3);
    const int b     = swz >> 6;
    const int cout0 = ((swz >> 3) & 7) * 64;
    const int r0    = (swz & 7) * 8;

    if ((bid >> 8) & 1) __builtin_amdgcn_s_sleep(60);   // ~3840 cyc anti-phase

    const int nx = (wv < 2) ? 11 : 10;             // X slots per wave (42 total)

    // ---- W staging source offsets into chunk-major wbf3 (+147456/chunk)
    int gw[9];
#pragma unroll
    for (int t = 0; t < 9; ++t) {
        int L = (wv * 9 + t) * 64 + lane;          // physical 16B-block in wt
        int tap = L >> 8, win = (L >> 5) & 7, k = (L >> 3) & 3, s = L & 7;
        int c = win * 8 + ((s ^ (k * 2)) & 7);     // logical cout_local
        gw[t] = tap * 16384 + (cout0 + c) * 32 + k * 8;
    }
    int gxo[11];
#pragma unroll
    for (int t = 0; t < 11; ++t) {
        if (t < nx) {
            int L = (wv + 4 * t) * 64 + lane;      // physical block in xs, slot u=wv+4t
            int k = (L >> 3) & 3, s = L & 7;
            int p = ((L >> 5) << 3) | ((s ^ (k * 2)) & 7);
            p = min(p, 659);                        // pad-region lanes: safe duplicate
            int row = p / 66, col = p - row * 66;
            int gy = min(max(r0 - 1 + row, 0), 63);
            int gx = min(max(col - 1, 0), 63);
            gxo[t] = (((b * 64 + gy) * 64 + gx) << 9) + k * 8;   // xm element offset
        } else gxo[t] = 0;
    }

    f32x4 acc[2][4][4] = {};
    const int base_af = (l15 >> 3) * 512 + l4 * 128 + (((l15 & 7) ^ (l4 * 2)) & 7) * 16;

    for (int c0 = 0; c0 < 512; c0 += 32) {
        const int wco = (c0 >> 5) * 147456;        // chunk-major W slice offset
        __syncthreads();                            // prev chunk's readers done
        // ---- stage W (linear LDS dest, pre-swizzled chunk-major source)
#pragma unroll
        for (int t = 0; t < 9; ++t)
            gload16(wbf3 + gw[t] + wco, (char*)wt + (wv * 9 + t) * 1024);
        // ---- stage X
        if (XPRE) {
#pragma unroll
            for (int t = 0; t < 11; ++t)
                if (t < nx)
                    gload16(xm + gxo[t] + c0, (char*)xs + (wv + 4 * t) * 1024);
        } else {
#pragma unroll
            for (int t = 0; t < 11; ++t) {
                if (t < nx) {
                    int L = (wv + 4 * t) * 64 + lane;
                    int k = (L >> 3) & 3, s = L & 7;
                    int p = ((L >> 5) << 3) | ((s ^ (k * 2)) & 7);
                    p = min(p, 659);
                    int row = p / 66, col = p - row * 66;
                    int gy = min(max(r0 - 1 + row, 0), 63);
                    int gx = min(max(col - 1, 0), 63);
                    const float* xp = x + ((size_t)(b * 512 + c0 + k * 8)) * 4096 + gy * 64 + gx;
                    const float* sc = style_c + b * 512 + c0 + k * 8;
                    ushort_t tmp[8];
#pragma unroll
                    for (int e = 0; e < 8; ++e)
                        tmp[e] = f2bf(xp[(size_t)e * 4096] * sc[e]);
                    *(bhalf8*)((char*)xs + (size_t)L * 16) = *(const bhalf8*)tmp;
                }
            }
        }
        asm volatile("s_waitcnt vmcnt(0)" ::: "memory");
        __syncthreads();

        // ---- compute: dx-major, af held for all dy, bfr per input row
#pragma unroll
        for (int dx = 0; dx < 3; ++dx) {
            bhalf8 af[3][4];
#pragma unroll
            for (int dy = 0; dy < 3; ++dy)
#pragma unroll
                for (int m = 0; m < 4; ++m)
                    af[dy][m] = *(const bhalf8*)((const char*)wt + base_af + (dy * 3 + dx) * 4096 + m * 1024);
#pragma unroll
            for (int ri = 0; ri < 4; ++ri) {
                const int p0 = (wv * 2 + ri) * 66 + dx + l15;
                const int bb = (p0 >> 3) * 512 + l4 * 128 + (((p0 & 7) ^ (l4 * 2)) & 7) * 16;
                bhalf8 bfr[4];
#pragma unroll
                for (int n = 0; n < 4; ++n)
                    bfr[n] = *(const bhalf8*)((const char*)xs + bb + n * 1024);
#pragma unroll
                for (int dy = 0; dy < 3; ++dy) {
                    const int r_out = ri - dy;
                    if (r_out < 0 || r_out > 1) continue;
#pragma unroll
                    for (int m = 0; m < 4; ++m)
#pragma unroll
                        for (int n = 0; n < 4; ++n)
                            acc[r_out][m][n] = __builtin_amdgcn_mfma_f32_16x16x32_bf16(
                                af[dy][m], bfr[n], acc[r_out][m][n], 0, 0, 0);
                }
            }
        }
    }

    // ---- epilogue: demodulate + store (C/D: col=lane&15, row=(lane>>4)*4+reg)
#pragma unroll
    for (int r_out = 0; r_out < 2; ++r_out) {
        const int orow = r0 + wv * 2 + r_out;
#pragma unroll
        for (int m = 0; m < 4; ++m) {
#pragma unroll
            for (int r = 0; r < 4; ++r) {
                int cout = cout0 + m * 16 + l4 * 4 + r;
                float sg = sig[b * 512 + cout];
                float* op = out + (((size_t)b * 512 + cout) * 64 + orow) * 64;
#pragma unroll
                for (int n = 0; n < 4; ++n)
                    op[n * 16 + l15] = acc[r_out][m][n][r] * sg;
            }
        }
    }
}

// ---------------- launch ----------------------------------------------------
extern "C" void kernel_launch(void* const* d_in, const int* in_sizes, int n_in,
                              void* d_out, int out_size, void* d_ws, size_t ws_size,
                              hipStream_t stream) {
    const float* x  = (const float*)d_in[0];
    const float* s  = (const float*)d_in[1];
    const float* w0 = (const float*)d_in[2];
    const float* b0 = (const float*)d_in[3];
    const float* a0 = (const float*)d_in[4];
    const float* w1 = (const float*)d_in[5];
    const float* b1 = (const float*)d_in[6];
    const float* a1 = (const float*)d_in[7];
    const float* sw = (const float*)d_in[8];
    const float* sb = (const float*)d_in[9];
    const float* cw = (const float*)d_in[10];
    float* out = (float*)d_out;

    // workspace layout (f32 elements unless noted)
    float*    style_c = (float*)d_ws;                       // 8192
    float*    sig     = style_c + 8192;                     // 8192
    float*    zt0     = sig + 8192;                         // 8192
    float*    zt1     = zt0 + 8192;                         // 8192
    float*    wsq     = zt1 + 8192;                         // 262144
    ushort_t* wbf3    = (ushort_t*)(wsq + 262144);          // 2359296 bf16
    ushort_t* xm      = (ushort_t*)((char*)d_ws + 5898240); // 33554432 bf16 (67.1 MB)
    const bool xpre = ws_size >= 73007104ull;

    wsqbf_k<<<1024, 256, 0, stream>>>(cw, wsq, wbf3);
    map_layer_k<<<dim3(8, 16), 256, 0, stream>>>(s,   w0, b0, a0, zt0,     0);
    map_layer_k<<<dim3(8, 16), 256, 0, stream>>>(zt0, w1, b1, a1, zt1,     0);
    map_layer_k<<<dim3(8, 16), 256, 0, stream>>>(zt1, sw, sb, a1, style_c, 1);
    sigma_k<<<dim3(16, 16), 256, 0, stream>>>(style_c, wsq, sig);
    if (xpre) {
        xmod_k<<<dim3(64, 16), 256, 0, stream>>>(x, style_c, xm);
        conv_k<true><<<1024, 256, 0, stream>>>(x, xm, wbf3, style_c, sig, out);
    } else {
        conv_k<false><<<1024, 256, 0, stream>>>(x, xm, wbf3, style_c, sig, out);
    }
}

// Round 9
// 292.608 us; speedup vs baseline: 1.2925x; 1.0303x over previous
//
#include <hip/hip_runtime.h>

typedef unsigned short ushort_t;
typedef unsigned int uint_t;
typedef __attribute__((ext_vector_type(8))) short bhalf8;   // 8 bf16 (4 VGPRs)
typedef __attribute__((ext_vector_type(4))) float f32x4;

#define C_LIN  0.04419417382415922f     // 1/sqrt(512)
#define C_CONV 0.014731391274719738f    // 1/sqrt(512*9)

__device__ __forceinline__ ushort_t f2bf(float f) {
    uint_t u = __float_as_uint(f);
    u += 0x7fffu + ((u >> 16) & 1u);    // round-to-nearest-even
    return (ushort_t)(u >> 16);
}

__device__ __forceinline__ void gload16(const void* g, void* l) {
    __builtin_amdgcn_global_load_lds((const __attribute__((address_space(1))) void*)g,
                                     (__attribute__((address_space(3))) void*)l, 16, 0, 0);
}

// ---------------- mapping-network layer: zout = act(zin @ (w*C_LIN)^T + b) --
__global__ void map_layer_k(const float* __restrict__ zin, const float* __restrict__ w,
                            const float* __restrict__ bias, const float* __restrict__ alpha,
                            float* __restrict__ zout, int final_) {
    __shared__ float zs[512];
    const int b = blockIdx.y, tid = threadIdx.x;
    if (tid < 128) ((float4*)zs)[tid] = ((const float4*)(zin + b * 512))[tid];
    __syncthreads();
    const int j = blockIdx.x * 64 + (tid >> 2);
    const int part = (tid & 3) * 128;
    const float4* wr = (const float4*)(w + (size_t)j * 512 + part);
    const float* zp = zs + part;
    float acc = 0.f;
#pragma unroll 8
    for (int i = 0; i < 32; ++i) {
        float4 w4 = wr[i];
        acc += w4.x * zp[4*i] + w4.y * zp[4*i+1] + w4.z * zp[4*i+2] + w4.w * zp[4*i+3];
    }
    acc += __shfl_xor(acc, 1);
    acc += __shfl_xor(acc, 2);
    if ((tid & 3) == 0) {
        acc = acc * C_LIN + bias[j];
        if (final_) acc *= C_CONV;                       // fold c_conv into style
        else        acc = acc >= 0.f ? acc : alpha[j] * acc;
        zout[b * 512 + j] = acc;
    }
}

// ---- fused prep: wsq[co][ci] = sum_tap cw^2 ; wbf[tap][co][ci] = bf16(cw) --
__global__ void wsqbf_k(const float* __restrict__ cw, float* __restrict__ wsq,
                        ushort_t* __restrict__ wbf) {
    int idx = blockIdx.x * 256 + threadIdx.x;   // cout*512 + ci, < 262144
    const float* p = cw + (size_t)idx * 9;
    float v[9], sum = 0.f;
#pragma unroll
    for (int k = 0; k < 9; ++k) { v[k] = p[k]; sum += v[k] * v[k]; }
    wsq[idx] = sum;
#pragma unroll
    for (int k = 0; k < 9; ++k)
        wbf[(size_t)k * 262144 + idx] = f2bf(v[k]);
}

// ---------------- sigma_inv[b][cout], 256 blocks ----------------------------
__global__ void sigma_k(const float* __restrict__ style_c, const float* __restrict__ wsq,
                        float* __restrict__ sig) {
    __shared__ float s2[512];
    const int b = blockIdx.y, cb = blockIdx.x, tid = threadIdx.x;
    if (tid < 128) {
        float4 sv = ((const float4*)(style_c + b * 512))[tid];
        s2[4*tid]   = sv.x * sv.x; s2[4*tid+1] = sv.y * sv.y;
        s2[4*tid+2] = sv.z * sv.z; s2[4*tid+3] = sv.w * sv.w;
    }
    __syncthreads();
    const int c = cb * 32 + (tid >> 3);
    const int part = (tid & 7) * 64;
    const float4* wr = (const float4*)(wsq + (size_t)c * 512 + part);
    const float* zp = s2 + part;
    float acc = 0.f;
#pragma unroll
    for (int i = 0; i < 16; ++i) {
        float4 w = wr[i];
        acc += w.x * zp[4*i] + w.y * zp[4*i+1] + w.z * zp[4*i+2] + w.w * zp[4*i+3];
    }
    acc += __shfl_xor(acc, 1);
    acc += __shfl_xor(acc, 2);
    acc += __shfl_xor(acc, 4);
    if ((tid & 7) == 0) sig[b * 512 + c] = 1.0f / sqrtf(acc + 1e-8f);
}

// ---------------- x -> bf16 NHWC, style-modulated ---------------------------
__global__ void xmod_k(const float* __restrict__ x, const float* __restrict__ style_c,
                       ushort_t* __restrict__ xm) {
    const int y = blockIdx.x, b = blockIdx.y, tid = threadIdx.x;
    const float* xp = x + ((size_t)b * 512) * 4096 + y * 64;            // x[b][ci][y][0]
    ushort_t* op = xm + (((size_t)b * 64 + y) * 64) * 512;              // xm[b][y][x][ci]
    __shared__ ushort_t tile[32][68];
    for (int cin0 = 0; cin0 < 512; cin0 += 32) {
#pragma unroll
        for (int t = 0; t < 2; ++t) {                                   // float4 loads
            int i = tid + t * 256;                                      // < 512
            int ci = i >> 4, x4 = i & 15;
            float4 v = *(const float4*)(xp + (size_t)(cin0 + ci) * 4096 + x4 * 4);
            float sc = style_c[b * 512 + cin0 + ci];
            tile[ci][x4*4]   = f2bf(v.x * sc); tile[ci][x4*4+1] = f2bf(v.y * sc);
            tile[ci][x4*4+2] = f2bf(v.z * sc); tile[ci][x4*4+3] = f2bf(v.w * sc);
        }
        __syncthreads();
#pragma unroll
        for (int t = 0; t < 4; ++t) {                                   // ushort2 stores
            int i = tid + t * 256;                                      // < 1024
            int xc = i >> 4, c2 = i & 15;
            ushort2 pr;
            pr.x = tile[c2*2][xc]; pr.y = tile[c2*2+1][xc];
            *(ushort2*)(op + (size_t)xc * 512 + cin0 + c2 * 2) = pr;
        }
        __syncthreads();
    }
}

// ---------------- implicit-GEMM conv via 16x16x32 MFMA ----------------------
// Round-3 proven structure (67% MfmaUtil, 0 bank conflicts): 256 threads,
// 2 blocks/CU, W+X single-buffered, per-chunk stage -> drain -> compute.
// Co-resident blocks run in phase (L2 sharing) and overlap each other's
// drains. LDS sigma-swizzle on 16B blocks within 32-block windows:
//   physical (k=bits[4:3], s=bits[2:0]) holds logical (pos = s^2k, group k).
template <bool XPRE>
__global__ __launch_bounds__(256, 2)
void conv_k(const float* __restrict__ x, const ushort_t* __restrict__ xm,
            const ushort_t* __restrict__ wbf, const float* __restrict__ style_c,
            const float* __restrict__ sig, float* __restrict__ out) {
    __shared__ __align__(16) ushort_t wt[18432];   // 36864 B: 9 taps x 64 co x 32 ci
    __shared__ __align__(16) ushort_t xs[21504];   // 43008 B: 2688 16B-blocks

    const int tid  = threadIdx.x;
    const int lane = tid & 63;
    const int wv   = tid >> 6;
    const int l15  = lane & 15, l4 = lane >> 4;

    // XCD-aware bijective block swizzle (nwg=1024, 8 XCDs): batch-major chunks.
    const int bid = blockIdx.x;
    const int swz = (bid & 7) * 128 + (bid >> 3);
    const int b     = swz >> 6;
    const int cout0 = ((swz >> 3) & 7) * 64;
    const int r0    = (swz & 7) * 8;

    const int nx = (wv < 2) ? 11 : 10;             // X slots per wave (42 total)

    // ---- per-thread staging source offsets (element units, +c0 per chunk)
    int gw[9];
#pragma unroll
    for (int t = 0; t < 9; ++t) {
        int L = (wv * 9 + t) * 64 + lane;          // physical 16B-block in wt
        int tap = L >> 8, win = (L >> 5) & 7, k = (L >> 3) & 3, s = L & 7;
        int c = win * 8 + ((s ^ (k * 2)) & 7);     // logical cout_local
        gw[t] = ((tap * 512 + cout0 + c) << 9) + k * 8;
    }
    int gxo[11];
#pragma unroll
    for (int t = 0; t < 11; ++t) {
        if (t < nx) {
            int L = (wv + 4 * t) * 64 + lane;      // physical block in xs, slot u=wv+4t
            int k = (L >> 3) & 3, s = L & 7;
            int p = ((L >> 5) << 3) | ((s ^ (k * 2)) & 7);
            p = min(p, 659);                        // pad-region lanes: safe duplicate
            int row = p / 66, col = p - row * 66;
            int gy = min(max(r0 - 1 + row, 0), 63);
            int gx = min(max(col - 1, 0), 63);
            gxo[t] = (((b * 64 + gy) * 64 + gx) << 9) + k * 8;   // xm element offset
        } else gxo[t] = 0;
    }

    f32x4 acc[2][4][4] = {};
    const int base_af = (l15 >> 3) * 512 + l4 * 128 + (((l15 & 7) ^ (l4 * 2)) & 7) * 16;

    for (int c0 = 0; c0 < 512; c0 += 32) {
        __syncthreads();                            // prev chunk's readers done
        // ---- stage W (linear LDS dest, pre-swizzled global source)
#pragma unroll
        for (int t = 0; t < 9; ++t)
            gload16(wbf + gw[t] + c0, (char*)wt + (wv * 9 + t) * 1024);
        // ---- stage X
        if (XPRE) {
#pragma unroll
            for (int t = 0; t < 11; ++t)
                if (t < nx)
                    gload16(xm + gxo[t] + c0, (char*)xs + (wv + 4 * t) * 1024);
        } else {
#pragma unroll
            for (int t = 0; t < 11; ++t) {
                if (t < nx) {
                    int L = (wv + 4 * t) * 64 + lane;
                    int k = (L >> 3) & 3, s = L & 7;
                    int p = ((L >> 5) << 3) | ((s ^ (k * 2)) & 7);
                    p = min(p, 659);
                    int row = p / 66, col = p - row * 66;
                    int gy = min(max(r0 - 1 + row, 0), 63);
                    int gx = min(max(col - 1, 0), 63);
                    const float* xp = x + ((size_t)(b * 512 + c0 + k * 8)) * 4096 + gy * 64 + gx;
                    const float* sc = style_c + b * 512 + c0 + k * 8;
                    ushort_t tmp[8];
#pragma unroll
                    for (int e = 0; e < 8; ++e)
                        tmp[e] = f2bf(xp[(size_t)e * 4096] * sc[e]);
                    *(bhalf8*)((char*)xs + (size_t)L * 16) = *(const bhalf8*)tmp;
                }
            }
        }
        asm volatile("s_waitcnt vmcnt(0)" ::: "memory");
        __syncthreads();

        // ---- compute: dx-major, af held for all dy, bfr per input row
#pragma unroll
        for (int dx = 0; dx < 3; ++dx) {
            bhalf8 af[3][4];
#pragma unroll
            for (int dy = 0; dy < 3; ++dy)
#pragma unroll
                for (int m = 0; m < 4; ++m)
                    af[dy][m] = *(const bhalf8*)((const char*)wt + base_af + (dy * 3 + dx) * 4096 + m * 1024);
#pragma unroll
            for (int ri = 0; ri < 4; ++ri) {
                const int p0 = (wv * 2 + ri) * 66 + dx + l15;
                const int bb = (p0 >> 3) * 512 + l4 * 128 + (((p0 & 7) ^ (l4 * 2)) & 7) * 16;
                bhalf8 bfr[4];
#pragma unroll
                for (int n = 0; n < 4; ++n)
                    bfr[n] = *(const bhalf8*)((const char*)xs + bb + n * 1024);
#pragma unroll
                for (int dy = 0; dy < 3; ++dy) {
                    const int r_out = ri - dy;
                    if (r_out < 0 || r_out > 1) continue;
#pragma unroll
                    for (int m = 0; m < 4; ++m)
#pragma unroll
                        for (int n = 0; n < 4; ++n)
                            acc[r_out][m][n] = __builtin_amdgcn_mfma_f32_16x16x32_bf16(
                                af[dy][m], bfr[n], acc[r_out][m][n], 0, 0, 0);
                }
            }
        }
    }

    // ---- epilogue: demodulate + store (C/D: col=lane&15, row=(lane>>4)*4+reg)
#pragma unroll
    for (int r_out = 0; r_out < 2; ++r_out) {
        const int orow = r0 + wv * 2 + r_out;
#pragma unroll
        for (int m = 0; m < 4; ++m) {
#pragma unroll
            for (int r = 0; r < 4; ++r) {
                int cout = cout0 + m * 16 + l4 * 4 + r;
                float sg = sig[b * 512 + cout];
                float* op = out + (((size_t)b * 512 + cout) * 64 + orow) * 64;
#pragma unroll
                for (int n = 0; n < 4; ++n)
                    op[n * 16 + l15] = acc[r_out][m][n][r] * sg;
            }
        }
    }
}

// ---------------- launch ----------------------------------------------------
extern "C" void kernel_launch(void* const* d_in, const int* in_sizes, int n_in,
                              void* d_out, int out_size, void* d_ws, size_t ws_size,
                              hipStream_t stream) {
    const float* x  = (const float*)d_in[0];
    const float* s  = (const float*)d_in[1];
    const float* w0 = (const float*)d_in[2];
    const float* b0 = (const float*)d_in[3];
    const float* a0 = (const float*)d_in[4];
    const float* w1 = (const float*)d_in[5];
    const float* b1 = (const float*)d_in[6];
    const float* a1 = (const float*)d_in[7];
    const float* sw = (const float*)d_in[8];
    const float* sb = (const float*)d_in[9];
    const float* cw = (const float*)d_in[10];
    float* out = (float*)d_out;

    // workspace layout (f32 elements unless noted)
    float*    style_c = (float*)d_ws;                       // 8192
    float*    sig     = style_c + 8192;                     // 8192
    float*    zt0     = sig + 8192;                         // 8192
    float*    zt1     = zt0 + 8192;                         // 8192
    float*    wsq     = zt1 + 8192;                         // 262144
    ushort_t* wbf     = (ushort_t*)(wsq + 262144);          // 2359296 bf16
    ushort_t* xm      = (ushort_t*)((char*)d_ws + 5898240); // 33554432 bf16 (67.1 MB)
    const bool xpre = ws_size >= 73007104ull;

    wsqbf_k<<<1024, 256, 0, stream>>>(cw, wsq, wbf);
    map_layer_k<<<dim3(8, 16), 256, 0, stream>>>(s,   w0, b0, a0, zt0,     0);
    map_layer_k<<<dim3(8, 16), 256, 0, stream>>>(zt0, w1, b1, a1, zt1,     0);
    map_layer_k<<<dim3(8, 16), 256, 0, stream>>>(zt1, sw, sb, a1, style_c, 1);
    sigma_k<<<dim3(16, 16), 256, 0, stream>>>(style_c, wsq, sig);
    if (xpre) {
        xmod_k<<<dim3(64, 16), 256, 0, stream>>>(x, style_c, xm);
        conv_k<true><<<1024, 256, 0, stream>>>(x, xm, wbf, style_c, sig, out);
    } else {
        conv_k<false><<<1024, 256, 0, stream>>>(x, xm, wbf, style_c, sig, out);
    }
}

// Round 10
// 287.289 us; speedup vs baseline: 1.3164x; 1.0185x over previous
//
#include <hip/hip_runtime.h>

typedef unsigned short ushort_t;
typedef unsigned int uint_t;
typedef __attribute__((ext_vector_type(8))) short bhalf8;   // 8 bf16 (4 VGPRs)
typedef __attribute__((ext_vector_type(4))) float f32x4;

#define C_LIN  0.04419417382415922f     // 1/sqrt(512)
#define C_CONV 0.014731391274719738f    // 1/sqrt(512*9)

__device__ __forceinline__ ushort_t f2bf(float f) {
    uint_t u = __float_as_uint(f);
    u += 0x7fffu + ((u >> 16) & 1u);    // round-to-nearest-even
    return (ushort_t)(u >> 16);
}

__device__ __forceinline__ void gload16(const void* g, void* l) {
    __builtin_amdgcn_global_load_lds((const __attribute__((address_space(1))) void*)g,
                                     (__attribute__((address_space(3))) void*)l, 16, 0, 0);
}

// ---------------- prep1: [0,1024) wsqbf ; [1024,1152) mapping layer 0 -------
// wsqbf: wsq[co][ci] = sum_tap cw^2 ; wbf[tap][co][ci] = bf16(cw)
//   coalesced: 576 float4 per block -> LDS bounce -> stride-9 LDS reads
//   (9 coprime 32 -> conflict-free).
// map0: zt0 = prelu(s @ (w0*C_LIN)^T + b0, a0)
__global__ void prep1_k(const float* __restrict__ cw, float* __restrict__ wsq,
                        ushort_t* __restrict__ wbf,
                        const float* __restrict__ s, const float* __restrict__ w0,
                        const float* __restrict__ b0, const float* __restrict__ a0,
                        float* __restrict__ zt0) {
    __shared__ float ls[2304];
    const int tid = threadIdx.x;
    if (blockIdx.x < 1024) {
        const int bid = blockIdx.x;
        const float4* cw4 = (const float4*)cw + (size_t)bid * 576;
        ((float4*)ls)[tid] = cw4[tid];
        ((float4*)ls)[tid + 256] = cw4[tid + 256];
        if (tid < 64) ((float4*)ls)[tid + 512] = cw4[tid + 512];
        __syncthreads();
        const int idx = bid * 256 + tid;            // cout*512 + ci
        float v[9], sum = 0.f;
#pragma unroll
        for (int k = 0; k < 9; ++k) { v[k] = ls[tid * 9 + k]; sum += v[k] * v[k]; }
        wsq[idx] = sum;
#pragma unroll
        for (int k = 0; k < 9; ++k)
            wbf[(size_t)k * 262144 + idx] = f2bf(v[k]);
    } else {
        const int bx = blockIdx.x - 1024;           // 0..127
        const int b = bx >> 3;
        float* zs = ls;                             // reuse LDS (512 f32)
        if (tid < 128) ((float4*)zs)[tid] = ((const float4*)(s + b * 512))[tid];
        __syncthreads();
        const int j = (bx & 7) * 64 + (tid >> 2);
        const int part = (tid & 3) * 128;
        const float4* wr = (const float4*)(w0 + (size_t)j * 512 + part);
        const float* zp = zs + part;
        float acc = 0.f;
#pragma unroll 8
        for (int i = 0; i < 32; ++i) {
            float4 w4 = wr[i];
            acc += w4.x * zp[4*i] + w4.y * zp[4*i+1] + w4.z * zp[4*i+2] + w4.w * zp[4*i+3];
        }
        acc += __shfl_xor(acc, 1);
        acc += __shfl_xor(acc, 2);
        if ((tid & 3) == 0) {
            acc = acc * C_LIN + b0[j];
            zt0[b * 512 + j] = acc >= 0.f ? acc : a0[j] * acc;
        }
    }
}

// ---------------- mapping-network layer: zout = act(zin @ (w*C_LIN)^T + b) --
__global__ void map_layer_k(const float* __restrict__ zin, const float* __restrict__ w,
                            const float* __restrict__ bias, const float* __restrict__ alpha,
                            float* __restrict__ zout, int final_) {
    __shared__ float zs[512];
    const int b = blockIdx.y, tid = threadIdx.x;
    if (tid < 128) ((float4*)zs)[tid] = ((const float4*)(zin + b * 512))[tid];
    __syncthreads();
    const int j = blockIdx.x * 64 + (tid >> 2);
    const int part = (tid & 3) * 128;
    const float4* wr = (const float4*)(w + (size_t)j * 512 + part);
    const float* zp = zs + part;
    float acc = 0.f;
#pragma unroll 8
    for (int i = 0; i < 32; ++i) {
        float4 w4 = wr[i];
        acc += w4.x * zp[4*i] + w4.y * zp[4*i+1] + w4.z * zp[4*i+2] + w4.w * zp[4*i+3];
    }
    acc += __shfl_xor(acc, 1);
    acc += __shfl_xor(acc, 2);
    if ((tid & 3) == 0) {
        acc = acc * C_LIN + bias[j];
        if (final_) acc *= C_CONV;                       // fold c_conv into style
        else        acc = acc >= 0.f ? acc : alpha[j] * acc;
        zout[b * 512 + j] = acc;
    }
}

// ---------------- prep2: [0,256) sigma ; [256,1280) xmod --------------------
// sigma: sig[b][c] = rsqrt(dot(style^2, wsq[c]) + eps)
// xmod:  xm[b][y][x][ci] = bf16(x[b][ci][y][x] * style[b][ci])
__global__ void prep2_k(const float* __restrict__ style_c, const float* __restrict__ wsq,
                        float* __restrict__ sig,
                        const float* __restrict__ x, ushort_t* __restrict__ xm) {
    __shared__ float s2[512];
    __shared__ ushort_t tile[32][68];
    const int tid = threadIdx.x;
    if (blockIdx.x < 256) {
        const int cb = blockIdx.x & 15, b = blockIdx.x >> 4;
        if (tid < 128) {
            float4 sv = ((const float4*)(style_c + b * 512))[tid];
            s2[4*tid]   = sv.x * sv.x; s2[4*tid+1] = sv.y * sv.y;
            s2[4*tid+2] = sv.z * sv.z; s2[4*tid+3] = sv.w * sv.w;
        }
        __syncthreads();
        const int c = cb * 32 + (tid >> 3);
        const int part = (tid & 7) * 64;
        const float4* wr = (const float4*)(wsq + (size_t)c * 512 + part);
        const float* zp = s2 + part;
        float acc = 0.f;
#pragma unroll
        for (int i = 0; i < 16; ++i) {
            float4 w = wr[i];
            acc += w.x * zp[4*i] + w.y * zp[4*i+1] + w.z * zp[4*i+2] + w.w * zp[4*i+3];
        }
        acc += __shfl_xor(acc, 1);
        acc += __shfl_xor(acc, 2);
        acc += __shfl_xor(acc, 4);
        if ((tid & 7) == 0) sig[b * 512 + c] = 1.0f / sqrtf(acc + 1e-8f);
    } else {
        const int q = blockIdx.x - 256;
        const int y = q & 63, b = q >> 6;
        const float* xp = x + ((size_t)b * 512) * 4096 + y * 64;        // x[b][ci][y][0]
        ushort_t* op = xm + (((size_t)b * 64 + y) * 64) * 512;          // xm[b][y][x][ci]
        for (int cin0 = 0; cin0 < 512; cin0 += 32) {
#pragma unroll
            for (int t = 0; t < 2; ++t) {                               // float4 loads
                int i = tid + t * 256;                                  // < 512
                int ci = i >> 4, x4 = i & 15;
                float4 v = *(const float4*)(xp + (size_t)(cin0 + ci) * 4096 + x4 * 4);
                float sc = style_c[b * 512 + cin0 + ci];
                tile[ci][x4*4]   = f2bf(v.x * sc); tile[ci][x4*4+1] = f2bf(v.y * sc);
                tile[ci][x4*4+2] = f2bf(v.z * sc); tile[ci][x4*4+3] = f2bf(v.w * sc);
            }
            __syncthreads();
#pragma unroll
            for (int t = 0; t < 4; ++t) {                               // ushort2 stores
                int i = tid + t * 256;                                  // < 1024
                int xc = i >> 4, c2 = i & 15;
                ushort2 pr;
                pr.x = tile[c2*2][xc]; pr.y = tile[c2*2+1][xc];
                *(ushort2*)(op + (size_t)xc * 512 + cin0 + c2 * 2) = pr;
            }
            __syncthreads();
        }
    }
}

// ---------------- implicit-GEMM conv via 16x16x32 MFMA ----------------------
// FROZEN round-3/9 structure (3x reproduced: 222 us, 67% MfmaUtil, 0 bank
// conflicts): 256 threads, 2 blocks/CU, W+X single-buffered, per-chunk
// stage -> drain -> compute. Co-resident blocks overlap each other's drains.
// LDS sigma-swizzle on 16B blocks within 32-block windows:
//   physical (k=bits[4:3], s=bits[2:0]) holds logical (pos = s^2k, group k).
template <bool XPRE>
__global__ __launch_bounds__(256, 2)
void conv_k(const float* __restrict__ x, const ushort_t* __restrict__ xm,
            const ushort_t* __restrict__ wbf, const float* __restrict__ style_c,
            const float* __restrict__ sig, float* __restrict__ out) {
    __shared__ __align__(16) ushort_t wt[18432];   // 36864 B: 9 taps x 64 co x 32 ci
    __shared__ __align__(16) ushort_t xs[21504];   // 43008 B: 2688 16B-blocks

    const int tid  = threadIdx.x;
    const int lane = tid & 63;
    const int wv   = tid >> 6;
    const int l15  = lane & 15, l4 = lane >> 4;

    // XCD-aware bijective block swizzle (nwg=1024, 8 XCDs): batch-major chunks.
    const int bid = blockIdx.x;
    const int swz = (bid & 7) * 128 + (bid >> 3);
    const int b     = swz >> 6;
    const int cout0 = ((swz >> 3) & 7) * 64;
    const int r0    = (swz & 7) * 8;

    const int nx = (wv < 2) ? 11 : 10;             // X slots per wave (42 total)

    // ---- per-thread staging source offsets (element units, +c0 per chunk)
    int gw[9];
#pragma unroll
    for (int t = 0; t < 9; ++t) {
        int L = (wv * 9 + t) * 64 + lane;          // physical 16B-block in wt
        int tap = L >> 8, win = (L >> 5) & 7, k = (L >> 3) & 3, s = L & 7;
        int c = win * 8 + ((s ^ (k * 2)) & 7);     // logical cout_local
        gw[t] = ((tap * 512 + cout0 + c) << 9) + k * 8;
    }
    int gxo[11];
#pragma unroll
    for (int t = 0; t < 11; ++t) {
        if (t < nx) {
            int L = (wv + 4 * t) * 64 + lane;      // physical block in xs, slot u=wv+4t
            int k = (L >> 3) & 3, s = L & 7;
            int p = ((L >> 5) << 3) | ((s ^ (k * 2)) & 7);
            p = min(p, 659);                        // pad-region lanes: safe duplicate
            int row = p / 66, col = p - row * 66;
            int gy = min(max(r0 - 1 + row, 0), 63);
            int gx = min(max(col - 1, 0), 63);
            gxo[t] = (((b * 64 + gy) * 64 + gx) << 9) + k * 8;   // xm element offset
        } else gxo[t] = 0;
    }

    f32x4 acc[2][4][4] = {};
    const int base_af = (l15 >> 3) * 512 + l4 * 128 + (((l15 & 7) ^ (l4 * 2)) & 7) * 16;

    for (int c0 = 0; c0 < 512; c0 += 32) {
        __syncthreads();                            // prev chunk's readers done
        // ---- stage W (linear LDS dest, pre-swizzled global source)
#pragma unroll
        for (int t = 0; t < 9; ++t)
            gload16(wbf + gw[t] + c0, (char*)wt + (wv * 9 + t) * 1024);
        // ---- stage X
        if (XPRE) {
#pragma unroll
            for (int t = 0; t < 11; ++t)
                if (t < nx)
                    gload16(xm + gxo[t] + c0, (char*)xs + (wv + 4 * t) * 1024);
        } else {
#pragma unroll
            for (int t = 0; t < 11; ++t) {
                if (t < nx) {
                    int L = (wv + 4 * t) * 64 + lane;
                    int k = (L >> 3) & 3, s = L & 7;
                    int p = ((L >> 5) << 3) | ((s ^ (k * 2)) & 7);
                    p = min(p, 659);
                    int row = p / 66, col = p - row * 66;
                    int gy = min(max(r0 - 1 + row, 0), 63);
                    int gx = min(max(col - 1, 0), 63);
                    const float* xp = x + ((size_t)(b * 512 + c0 + k * 8)) * 4096 + gy * 64 + gx;
                    const float* sc = style_c + b * 512 + c0 + k * 8;
                    ushort_t tmp[8];
#pragma unroll
                    for (int e = 0; e < 8; ++e)
                        tmp[e] = f2bf(xp[(size_t)e * 4096] * sc[e]);
                    *(bhalf8*)((char*)xs + (size_t)L * 16) = *(const bhalf8*)tmp;
                }
            }
        }
        asm volatile("s_waitcnt vmcnt(0)" ::: "memory");
        __syncthreads();

        // ---- compute: dx-major, af held for all dy, bfr per input row
#pragma unroll
        for (int dx = 0; dx < 3; ++dx) {
            bhalf8 af[3][4];
#pragma unroll
            for (int dy = 0; dy < 3; ++dy)
#pragma unroll
                for (int m = 0; m < 4; ++m)
                    af[dy][m] = *(const bhalf8*)((const char*)wt + base_af + (dy * 3 + dx) * 4096 + m * 1024);
#pragma unroll
            for (int ri = 0; ri < 4; ++ri) {
                const int p0 = (wv * 2 + ri) * 66 + dx + l15;
                const int bb = (p0 >> 3) * 512 + l4 * 128 + (((p0 & 7) ^ (l4 * 2)) & 7) * 16;
                bhalf8 bfr[4];
#pragma unroll
                for (int n = 0; n < 4; ++n)
                    bfr[n] = *(const bhalf8*)((const char*)xs + bb + n * 1024);
#pragma unroll
                for (int dy = 0; dy < 3; ++dy) {
                    const int r_out = ri - dy;
                    if (r_out < 0 || r_out > 1) continue;
#pragma unroll
                    for (int m = 0; m < 4; ++m)
#pragma unroll
                        for (int n = 0; n < 4; ++n)
                            acc[r_out][m][n] = __builtin_amdgcn_mfma_f32_16x16x32_bf16(
                                af[dy][m], bfr[n], acc[r_out][m][n], 0, 0, 0);
                }
            }
        }
    }

    // ---- epilogue: demodulate + store (C/D: col=lane&15, row=(lane>>4)*4+reg)
#pragma unroll
    for (int r_out = 0; r_out < 2; ++r_out) {
        const int orow = r0 + wv * 2 + r_out;
#pragma unroll
        for (int m = 0; m < 4; ++m) {
#pragma unroll
            for (int r = 0; r < 4; ++r) {
                int cout = cout0 + m * 16 + l4 * 4 + r;
                float sg = sig[b * 512 + cout];
                float* op = out + (((size_t)b * 512 + cout) * 64 + orow) * 64;
#pragma unroll
                for (int n = 0; n < 4; ++n)
                    op[n * 16 + l15] = acc[r_out][m][n][r] * sg;
            }
        }
    }
}

// ---------------- launch ----------------------------------------------------
extern "C" void kernel_launch(void* const* d_in, const int* in_sizes, int n_in,
                              void* d_out, int out_size, void* d_ws, size_t ws_size,
                              hipStream_t stream) {
    const float* x  = (const float*)d_in[0];
    const float* s  = (const float*)d_in[1];
    const float* w0 = (const float*)d_in[2];
    const float* b0 = (const float*)d_in[3];
    const float* a0 = (const float*)d_in[4];
    const float* w1 = (const float*)d_in[5];
    const float* b1 = (const float*)d_in[6];
    const float* a1 = (const float*)d_in[7];
    const float* sw = (const float*)d_in[8];
    const float* sb = (const float*)d_in[9];
    const float* cw = (const float*)d_in[10];
    float* out = (float*)d_out;

    // workspace layout (f32 elements unless noted)
    float*    style_c = (float*)d_ws;                       // 8192
    float*    sig     = style_c + 8192;                     // 8192
    float*    zt0     = sig + 8192;                         // 8192
    float*    zt1     = zt0 + 8192;                         // 8192
    float*    wsq     = zt1 + 8192;                         // 262144
    ushort_t* wbf     = (ushort_t*)(wsq + 262144);          // 2359296 bf16
    ushort_t* xm      = (ushort_t*)((char*)d_ws + 5898240); // 33554432 bf16 (67.1 MB)
    const bool xpre = ws_size >= 73007104ull;

    prep1_k<<<1152, 256, 0, stream>>>(cw, wsq, wbf, s, w0, b0, a0, zt0);
    map_layer_k<<<dim3(8, 16), 256, 0, stream>>>(zt0, w1, b1, a1, zt1, 0);
    map_layer_k<<<dim3(8, 16), 256, 0, stream>>>(zt1, sw, sb, a1, style_c, 1);
    if (xpre) {
        prep2_k<<<1280, 256, 0, stream>>>(style_c, wsq, sig, x, xm);
        conv_k<true><<<1024, 256, 0, stream>>>(x, xm, wbf, style_c, sig, out);
    } else {
        prep2_k<<<256, 256, 0, stream>>>(style_c, wsq, sig, x, xm);
        conv_k<false><<<1024, 256, 0, stream>>>(x, xm, wbf, style_c, sig, out);
    }
}

// Round 11
// 283.076 us; speedup vs baseline: 1.3360x; 1.0149x over previous
//
#include <hip/hip_runtime.h>
#include <hip/hip_bf16.h>

typedef unsigned short ushort_t;
typedef unsigned int uint_t;
typedef __attribute__((ext_vector_type(8))) short bhalf8;   // 8 bf16 (4 VGPRs)
typedef __attribute__((ext_vector_type(4))) float f32x4;

#define C_LIN  0.04419417382415922f     // 1/sqrt(512)
#define C_CONV 0.014731391274719738f    // 1/sqrt(512*9)

__device__ __forceinline__ ushort_t f2bf(float f) {
    uint_t u = __float_as_uint(f);
    u += 0x7fffu + ((u >> 16) & 1u);    // round-to-nearest-even
    return (ushort_t)(u >> 16);
}

__device__ __forceinline__ void gload16(const void* g, void* l) {
    __builtin_amdgcn_global_load_lds((const __attribute__((address_space(1))) void*)g,
                                     (__attribute__((address_space(3))) void*)l, 16, 0, 0);
}

// ---------------- prep1: [0,1024) wsqbf ; [1024,1152) mapping layer 0 -------
__global__ void prep1_k(const float* __restrict__ cw, float* __restrict__ wsq,
                        ushort_t* __restrict__ wbf,
                        const float* __restrict__ s, const float* __restrict__ w0,
                        const float* __restrict__ b0, const float* __restrict__ a0,
                        float* __restrict__ zt0) {
    __shared__ float ls[2304];
    const int tid = threadIdx.x;
    if (blockIdx.x < 1024) {
        const int bid = blockIdx.x;
        const float4* cw4 = (const float4*)cw + (size_t)bid * 576;
        ((float4*)ls)[tid] = cw4[tid];
        ((float4*)ls)[tid + 256] = cw4[tid + 256];
        if (tid < 64) ((float4*)ls)[tid + 512] = cw4[tid + 512];
        __syncthreads();
        const int idx = bid * 256 + tid;            // cout*512 + ci
        float v[9], sum = 0.f;
#pragma unroll
        for (int k = 0; k < 9; ++k) { v[k] = ls[tid * 9 + k]; sum += v[k] * v[k]; }
        wsq[idx] = sum;
#pragma unroll
        for (int k = 0; k < 9; ++k)
            wbf[(size_t)k * 262144 + idx] = f2bf(v[k]);
    } else {
        const int bx = blockIdx.x - 1024;           // 0..127
        const int b = bx >> 3;
        float* zs = ls;                             // reuse LDS (512 f32)
        if (tid < 128) ((float4*)zs)[tid] = ((const float4*)(s + b * 512))[tid];
        __syncthreads();
        const int j = (bx & 7) * 64 + (tid >> 2);
        const int part = (tid & 3) * 128;
        const float4* wr = (const float4*)(w0 + (size_t)j * 512 + part);
        const float* zp = zs + part;
        float acc = 0.f;
#pragma unroll 8
        for (int i = 0; i < 32; ++i) {
            float4 w4 = wr[i];
            acc += w4.x * zp[4*i] + w4.y * zp[4*i+1] + w4.z * zp[4*i+2] + w4.w * zp[4*i+3];
        }
        acc += __shfl_xor(acc, 1);
        acc += __shfl_xor(acc, 2);
        if ((tid & 3) == 0) {
            acc = acc * C_LIN + b0[j];
            zt0[b * 512 + j] = acc >= 0.f ? acc : a0[j] * acc;
        }
    }
}

// ---------------- mapping-network layer: zout = act(zin @ (w*C_LIN)^T + b) --
__global__ void map_layer_k(const float* __restrict__ zin, const float* __restrict__ w,
                            const float* __restrict__ bias, const float* __restrict__ alpha,
                            float* __restrict__ zout, int final_) {
    __shared__ float zs[512];
    const int b = blockIdx.y, tid = threadIdx.x;
    if (tid < 128) ((float4*)zs)[tid] = ((const float4*)(zin + b * 512))[tid];
    __syncthreads();
    const int j = blockIdx.x * 64 + (tid >> 2);
    const int part = (tid & 3) * 128;
    const float4* wr = (const float4*)(w + (size_t)j * 512 + part);
    const float* zp = zs + part;
    float acc = 0.f;
#pragma unroll 8
    for (int i = 0; i < 32; ++i) {
        float4 w4 = wr[i];
        acc += w4.x * zp[4*i] + w4.y * zp[4*i+1] + w4.z * zp[4*i+2] + w4.w * zp[4*i+3];
    }
    acc += __shfl_xor(acc, 1);
    acc += __shfl_xor(acc, 2);
    if ((tid & 3) == 0) {
        acc = acc * C_LIN + bias[j];
        if (final_) acc *= C_CONV;                       // fold c_conv into style
        else        acc = acc >= 0.f ? acc : alpha[j] * acc;
        zout[b * 512 + j] = acc;
    }
}

// ---------------- prep2: [0,256) sigma ; [256,1280) xmod --------------------
// xmod per (b,y): ci-tile 64, LDS [64 ci][68 x]:
//   load:  float4/lane coalesced, cvt_pk bf16 pairs, one 8B LDS write
//          (16 x4-lanes x 2 dwords = conflict-free)
//   store: ushort4 (8B) global, 16 ci4-lanes -> 128B contiguous segments
__global__ void prep2_k(const float* __restrict__ style_c, const float* __restrict__ wsq,
                        float* __restrict__ sig,
                        const float* __restrict__ x, ushort_t* __restrict__ xm) {
    __shared__ float s2[512];
    __shared__ __align__(8) ushort_t tile[64 * 68];
    const int tid = threadIdx.x;
    if (blockIdx.x < 256) {
        const int cb = blockIdx.x & 15, b = blockIdx.x >> 4;
        if (tid < 128) {
            float4 sv = ((const float4*)(style_c + b * 512))[tid];
            s2[4*tid]   = sv.x * sv.x; s2[4*tid+1] = sv.y * sv.y;
            s2[4*tid+2] = sv.z * sv.z; s2[4*tid+3] = sv.w * sv.w;
        }
        __syncthreads();
        const int c = cb * 32 + (tid >> 3);
        const int part = (tid & 7) * 64;
        const float4* wr = (const float4*)(wsq + (size_t)c * 512 + part);
        const float* zp = s2 + part;
        float acc = 0.f;
#pragma unroll
        for (int i = 0; i < 16; ++i) {
            float4 w = wr[i];
            acc += w.x * zp[4*i] + w.y * zp[4*i+1] + w.z * zp[4*i+2] + w.w * zp[4*i+3];
        }
        acc += __shfl_xor(acc, 1);
        acc += __shfl_xor(acc, 2);
        acc += __shfl_xor(acc, 4);
        if ((tid & 7) == 0) sig[b * 512 + c] = 1.0f / sqrtf(acc + 1e-8f);
    } else {
        const int q = blockIdx.x - 256;
        const int y = q & 63, b = q >> 6;
        const float* xp = x + ((size_t)b * 512) * 4096 + y * 64;        // x[b][ci][y][0]
        ushort_t* op = xm + (((size_t)b * 64 + y) * 64) * 512;          // xm[b][y][x][ci]
        for (int cin0 = 0; cin0 < 512; cin0 += 64) {
#pragma unroll
            for (int t = 0; t < 4; ++t) {                               // load + cvt_pk + b64 LDS write
                int i = tid + t * 256;                                  // < 1024
                int ci = i >> 4, x4 = i & 15;
                float4 v = *(const float4*)(xp + (size_t)(cin0 + ci) * 4096 + x4 * 4);
                float sc = style_c[b * 512 + cin0 + ci];
                float2 p0; p0.x = v.x * sc; p0.y = v.y * sc;
                float2 p1; p1.x = v.z * sc; p1.y = v.w * sc;
                __hip_bfloat162 lo = __float22bfloat162_rn(p0);
                __hip_bfloat162 hi = __float22bfloat162_rn(p1);
                uint2 pk;
                pk.x = *(const uint_t*)&lo;
                pk.y = *(const uint_t*)&hi;
                *(uint2*)&tile[ci * 68 + x4 * 4] = pk;
            }
            __syncthreads();
#pragma unroll
            for (int t = 0; t < 4; ++t) {                               // ushort4 (8B) stores
                int i = tid + t * 256;                                  // < 1024
                int ci4 = i & 15, xc = i >> 4;
                ushort4 o;
                o.x = tile[(ci4 * 4 + 0) * 68 + xc];
                o.y = tile[(ci4 * 4 + 1) * 68 + xc];
                o.z = tile[(ci4 * 4 + 2) * 68 + xc];
                o.w = tile[(ci4 * 4 + 3) * 68 + xc];
                *(ushort4*)(op + (size_t)xc * 512 + cin0 + ci4 * 4) = o;
            }
            __syncthreads();
        }
    }
}

// ---------------- implicit-GEMM conv via 16x16x32 MFMA ----------------------
// FROZEN round-3/9 structure (4x reproduced: 222 us, 67% MfmaUtil, 0 bank
// conflicts): 256 threads, 2 blocks/CU, W+X single-buffered, per-chunk
// stage -> drain -> compute. Co-resident blocks overlap each other's drains.
// LDS sigma-swizzle on 16B blocks within 32-block windows:
//   physical (k=bits[4:3], s=bits[2:0]) holds logical (pos = s^2k, group k).
template <bool XPRE>
__global__ __launch_bounds__(256, 2)
void conv_k(const float* __restrict__ x, const ushort_t* __restrict__ xm,
            const ushort_t* __restrict__ wbf, const float* __restrict__ style_c,
            const float* __restrict__ sig, float* __restrict__ out) {
    __shared__ __align__(16) ushort_t wt[18432];   // 36864 B: 9 taps x 64 co x 32 ci
    __shared__ __align__(16) ushort_t xs[21504];   // 43008 B: 2688 16B-blocks

    const int tid  = threadIdx.x;
    const int lane = tid & 63;
    const int wv   = tid >> 6;
    const int l15  = lane & 15, l4 = lane >> 4;

    // XCD-aware bijective block swizzle (nwg=1024, 8 XCDs): batch-major chunks.
    const int bid = blockIdx.x;
    const int swz = (bid & 7) * 128 + (bid >> 3);
    const int b     = swz >> 6;
    const int cout0 = ((swz >> 3) & 7) * 64;
    const int r0    = (swz & 7) * 8;

    const int nx = (wv < 2) ? 11 : 10;             // X slots per wave (42 total)

    // ---- per-thread staging source offsets (element units, +c0 per chunk)
    int gw[9];
#pragma unroll
    for (int t = 0; t < 9; ++t) {
        int L = (wv * 9 + t) * 64 + lane;          // physical 16B-block in wt
        int tap = L >> 8, win = (L >> 5) & 7, k = (L >> 3) & 3, s = L & 7;
        int c = win * 8 + ((s ^ (k * 2)) & 7);     // logical cout_local
        gw[t] = ((tap * 512 + cout0 + c) << 9) + k * 8;
    }
    int gxo[11];
#pragma unroll
    for (int t = 0; t < 11; ++t) {
        if (t < nx) {
            int L = (wv + 4 * t) * 64 + lane;      // physical block in xs, slot u=wv+4t
            int k = (L >> 3) & 3, s = L & 7;
            int p = ((L >> 5) << 3) | ((s ^ (k * 2)) & 7);
            p = min(p, 659);                        // pad-region lanes: safe duplicate
            int row = p / 66, col = p - row * 66;
            int gy = min(max(r0 - 1 + row, 0), 63);
            int gx = min(max(col - 1, 0), 63);
            gxo[t] = (((b * 64 + gy) * 64 + gx) << 9) + k * 8;   // xm element offset
        } else gxo[t] = 0;
    }

    f32x4 acc[2][4][4] = {};
    const int base_af = (l15 >> 3) * 512 + l4 * 128 + (((l15 & 7) ^ (l4 * 2)) & 7) * 16;

    for (int c0 = 0; c0 < 512; c0 += 32) {
        __syncthreads();                            // prev chunk's readers done
        // ---- stage W (linear LDS dest, pre-swizzled global source)
#pragma unroll
        for (int t = 0; t < 9; ++t)
            gload16(wbf + gw[t] + c0, (char*)wt + (wv * 9 + t) * 1024);
        // ---- stage X
        if (XPRE) {
#pragma unroll
            for (int t = 0; t < 11; ++t)
                if (t < nx)
                    gload16(xm + gxo[t] + c0, (char*)xs + (wv + 4 * t) * 1024);
        } else {
#pragma unroll
            for (int t = 0; t < 11; ++t) {
                if (t < nx) {
                    int L = (wv + 4 * t) * 64 + lane;
                    int k = (L >> 3) & 3, s = L & 7;
                    int p = ((L >> 5) << 3) | ((s ^ (k * 2)) & 7);
                    p = min(p, 659);
                    int row = p / 66, col = p - row * 66;
                    int gy = min(max(r0 - 1 + row, 0), 63);
                    int gx = min(max(col - 1, 0), 63);
                    const float* xp = x + ((size_t)(b * 512 + c0 + k * 8)) * 4096 + gy * 64 + gx;
                    const float* sc = style_c + b * 512 + c0 + k * 8;
                    ushort_t tmp[8];
#pragma unroll
                    for (int e = 0; e < 8; ++e)
                        tmp[e] = f2bf(xp[(size_t)e * 4096] * sc[e]);
                    *(bhalf8*)((char*)xs + (size_t)L * 16) = *(const bhalf8*)tmp;
                }
            }
        }
        asm volatile("s_waitcnt vmcnt(0)" ::: "memory");
        __syncthreads();

        // ---- compute: dx-major, af held for all dy, bfr per input row
#pragma unroll
        for (int dx = 0; dx < 3; ++dx) {
            bhalf8 af[3][4];
#pragma unroll
            for (int dy = 0; dy < 3; ++dy)
#pragma unroll
                for (int m = 0; m < 4; ++m)
                    af[dy][m] = *(const bhalf8*)((const char*)wt + base_af + (dy * 3 + dx) * 4096 + m * 1024);
#pragma unroll
            for (int ri = 0; ri < 4; ++ri) {
                const int p0 = (wv * 2 + ri) * 66 + dx + l15;
                const int bb = (p0 >> 3) * 512 + l4 * 128 + (((p0 & 7) ^ (l4 * 2)) & 7) * 16;
                bhalf8 bfr[4];
#pragma unroll
                for (int n = 0; n < 4; ++n)
                    bfr[n] = *(const bhalf8*)((const char*)xs + bb + n * 1024);
#pragma unroll
                for (int dy = 0; dy < 3; ++dy) {
                    const int r_out = ri - dy;
                    if (r_out < 0 || r_out > 1) continue;
#pragma unroll
                    for (int m = 0; m < 4; ++m)
#pragma unroll
                        for (int n = 0; n < 4; ++n)
                            acc[r_out][m][n] = __builtin_amdgcn_mfma_f32_16x16x32_bf16(
                                af[dy][m], bfr[n], acc[r_out][m][n], 0, 0, 0);
                }
            }
        }
    }

    // ---- epilogue: demodulate + store (C/D: col=lane&15, row=(lane>>4)*4+reg)
#pragma unroll
    for (int r_out = 0; r_out < 2; ++r_out) {
        const int orow = r0 + wv * 2 + r_out;
#pragma unroll
        for (int m = 0; m < 4; ++m) {
#pragma unroll
            for (int r = 0; r < 4; ++r) {
                int cout = cout0 + m * 16 + l4 * 4 + r;
                float sg = sig[b * 512 + cout];
                float* op = out + (((size_t)b * 512 + cout) * 64 + orow) * 64;
#pragma unroll
                for (int n = 0; n < 4; ++n)
                    op[n * 16 + l15] = acc[r_out][m][n][r] * sg;
            }
        }
    }
}

// ---------------- launch ----------------------------------------------------
extern "C" void kernel_launch(void* const* d_in, const int* in_sizes, int n_in,
                              void* d_out, int out_size, void* d_ws, size_t ws_size,
                              hipStream_t stream) {
    const float* x  = (const float*)d_in[0];
    const float* s  = (const float*)d_in[1];
    const float* w0 = (const float*)d_in[2];
    const float* b0 = (const float*)d_in[3];
    const float* a0 = (const float*)d_in[4];
    const float* w1 = (const float*)d_in[5];
    const float* b1 = (const float*)d_in[6];
    const float* a1 = (const float*)d_in[7];
    const float* sw = (const float*)d_in[8];
    const float* sb = (const float*)d_in[9];
    const float* cw = (const float*)d_in[10];
    float* out = (float*)d_out;

    // workspace layout (f32 elements unless noted)
    float*    style_c = (float*)d_ws;                       // 8192
    float*    sig     = style_c + 8192;                     // 8192
    float*    zt0     = sig + 8192;                         // 8192
    float*    zt1     = zt0 + 8192;                         // 8192
    float*    wsq     = zt1 + 8192;                         // 262144
    ushort_t* wbf     = (ushort_t*)(wsq + 262144);          // 2359296 bf16
    ushort_t* xm      = (ushort_t*)((char*)d_ws + 5898240); // 33554432 bf16 (67.1 MB)
    const bool xpre = ws_size >= 73007104ull;

    prep1_k<<<1152, 256, 0, stream>>>(cw, wsq, wbf, s, w0, b0, a0, zt0);
    map_layer_k<<<dim3(8, 16), 256, 0, stream>>>(zt0, w1, b1, a1, zt1, 0);
    map_layer_k<<<dim3(8, 16), 256, 0, stream>>>(zt1, sw, sb, a1, style_c, 1);
    if (xpre) {
        prep2_k<<<1280, 256, 0, stream>>>(style_c, wsq, sig, x, xm);
        conv_k<true><<<1024, 256, 0, stream>>>(x, xm, wbf, style_c, sig, out);
    } else {
        prep2_k<<<256, 256, 0, stream>>>(style_c, wsq, sig, x, xm);
        conv_k<false><<<1024, 256, 0, stream>>>(x, xm, wbf, style_c, sig, out);
    }
}